// Round 1
// 423.449 us; speedup vs baseline: 1.0934x; 1.0934x over previous
//
#include <hip/hip_runtime.h>
#include <cstdint>
#include <cstddef>

#define EPI_QKV  0
#define EPI_F32  2
#define EPI_GELU 3
#define EPI_PART 4

typedef __attribute__((ext_vector_type(8))) short bfrag8;   // 8 bf16 (4 VGPRs)
typedef __attribute__((ext_vector_type(4))) float facc4;    // 4 fp32 acc

struct PtrQuad { unsigned short* p[4]; };

__device__ __forceinline__ unsigned short f2b(float x) {
  unsigned int u = __builtin_bit_cast(unsigned int, x);
  u += 0x7FFFu + ((u >> 16) & 1u);   // RNE
  return (unsigned short)(u >> 16);
}
__device__ __forceinline__ float b2f(unsigned short u) {
  unsigned int x = ((unsigned int)u) << 16;
  return __builtin_bit_cast(float, x);
}

__device__ __forceinline__ void gl2lds16(const unsigned short* g, unsigned short* l) {
  __builtin_amdgcn_global_load_lds(
      (const __attribute__((address_space(1))) unsigned int*)g,
      (__attribute__((address_space(3))) unsigned int*)l, 16, 0, 0);
}

// ---------------- elementwise fp32 -> bf16 ----------------
__global__ __launch_bounds__(256)
void cvt_bf16_kernel(const float* __restrict__ in, unsigned short* __restrict__ out, int n4) {
  const int i = blockIdx.x * 256 + threadIdx.x;
  if (i < n4) {
    const float4 v = ((const float4*)in)[i];
    ushort4 u;
    u.x = f2b(v.x); u.y = f2b(v.y); u.z = f2b(v.z); u.w = f2b(v.w);
    ((ushort4*)out)[i] = u;
  }
}

// ---------------- transpose + convert: in (K x N) fp32 -> out (N x K) bf16 ----------------
__global__ __launch_bounds__(256)
void transpose_cvt(const float* __restrict__ in, unsigned short* __restrict__ out,
                   int K, int N) {
  __shared__ float tile[32][33];
  const int n0 = blockIdx.x * 32;
  const int k0 = blockIdx.y * 32;
  const int tx = threadIdx.x & 31, ty = threadIdx.x >> 5;  // ty 0..7
#pragma unroll
  for (int i = 0; i < 32; i += 8)
    tile[ty + i][tx] = in[(size_t)(k0 + ty + i) * N + n0 + tx];
  __syncthreads();
#pragma unroll
  for (int i = 0; i < 32; i += 8)
    out[(size_t)(n0 + ty + i) * K + k0 + tx] = f2b(tile[tx][ty + i]);
}

// ---------------- GEMM: C = A(MxK') @ Bt(NxK')^T slice, bf16 MFMA, fused epilogues ------
// 128x128 tile, BK=32, 4 waves (2x2), 4x4 16x16x32 MFMA per wave. m97 structure.
template<int EPI>
__global__ __launch_bounds__(256, 2)
void gemm_bt(const unsigned short* __restrict__ A,
             const unsigned short* __restrict__ Bt,
             const float* __restrict__ bias,
             const float* __restrict__ bias2,
             const float* __restrict__ bias3,
             void* __restrict__ out, PtrQuad pq,
             int M, int N, int K, int ldk) {
  __shared__ unsigned short sA[128 * 32];
  __shared__ unsigned short sB[128 * 32];
  const int tid  = threadIdx.x;
  const int lane = tid & 63;
  const int wave = tid >> 6;
  const int l15  = lane & 15, l4 = lane >> 4;
  const int wr = wave >> 1, wc = wave & 1;
  const long row0 = (long)blockIdx.y * 128;
  const long col0 = (long)blockIdx.x * 128;
  const long k0   = (long)blockIdx.z * K;

  facc4 acc[4][4];
#pragma unroll
  for (int i = 0; i < 4; i++)
#pragma unroll
    for (int j = 0; j < 4; j++) acc[i][j] = (facc4)0.f;

  const int srow = tid >> 2;
  const int scol = (tid & 3) * 8;
  const unsigned short* Ap0 = A  + (row0 + srow) * (long)ldk + k0 + scol;
  const unsigned short* Ap1 = Ap0 + 64 * (long)ldk;
  const unsigned short* Bp0 = Bt + (col0 + srow) * (long)ldk + k0 + scol;
  const unsigned short* Bp1 = Bp0 + 64 * (long)ldk;
  const int wbase = (tid & ~63) * 8;
  unsigned short* sA0 = &sA[wbase];
  unsigned short* sA1 = &sA[2048 + wbase];
  unsigned short* sB0 = &sB[wbase];
  unsigned short* sB1 = &sB[2048 + wbase];

  const int aoff = (wr * 64 + l15) * 32 + l4 * 8;
  const int boff = (wc * 64 + l15) * 32 + l4 * 8;

  for (int kt = 0; kt < K; kt += 32) {
    gl2lds16(Ap0 + kt, sA0);
    gl2lds16(Ap1 + kt, sA1);
    gl2lds16(Bp0 + kt, sB0);
    gl2lds16(Bp1 + kt, sB1);
    __syncthreads();
    bfrag8 af[4], bf[4];
#pragma unroll
    for (int i = 0; i < 4; i++) af[i] = *(const bfrag8*)&sA[aoff + i * 512];
#pragma unroll
    for (int j = 0; j < 4; j++) bf[j] = *(const bfrag8*)&sB[boff + j * 512];
#pragma unroll
    for (int i = 0; i < 4; i++)
#pragma unroll
      for (int j = 0; j < 4; j++)
        acc[i][j] = __builtin_amdgcn_mfma_f32_16x16x32_bf16(af[i], bf[j], acc[i][j], 0, 0, 0);
    __syncthreads();
  }

#pragma unroll
  for (int i = 0; i < 4; i++) {
    const long m0 = row0 + wr * 64 + i * 16 + l4 * 4;
#pragma unroll
    for (int j = 0; j < 4; j++) {
      const long c = col0 + wc * 64 + j * 16 + l15;
      if constexpr (EPI == EPI_QKV) {
        const long which = c >> 10;
        const long cl = c & 1023;
        unsigned short* oq = (unsigned short*)out;
        if (which == 0) {
          const float bj = bias[cl];
#pragma unroll
          for (int r = 0; r < 4; r++)
            oq[(m0 + r) * 1024 + cl] = f2b((acc[i][j][r] + bj) * 0.03125f);
        } else if (which == 1) {
          const float bj = bias2[cl];
#pragma unroll
          for (int r = 0; r < 4; r++)
            (oq + 4194304)[(m0 + r) * 1024 + cl] = f2b(acc[i][j][r] + bj);
        } else {
          const float bj = bias3[cl];
          const long cc = cl >> 6, d = cl & 63;
#pragma unroll
          for (int r = 0; r < 4; r++) {
            const long m = m0 + r;
            const long nbb = m >> 10, rr = m & 1023;
            const long h = rr >> 6, rhi = rr & 63;
            const long s = rhi * 16 + cc;
            (oq + 8388608)[((nbb * 16 + h) * 64 + d) * 1024 + s] = f2b(acc[i][j][r] + bj);
          }
        }
      } else if constexpr (EPI == EPI_F32) {
        const float bj = bias[c];
        float* of = (float*)out;
#pragma unroll
        for (int r = 0; r < 4; r++) of[(m0 + r) * (long)N + c] = acc[i][j][r] + bj;
      } else if constexpr (EPI == EPI_PART) {
        unsigned short* ob = pq.p[blockIdx.z];
#pragma unroll
        for (int r = 0; r < 4; r++) ob[(m0 + r) * (long)N + c] = f2b(acc[i][j][r]);
      } else {  // EPI_GELU -> bf16
        const float bj = bias[c];
        unsigned short* ob = (unsigned short*)out;
#pragma unroll
        for (int r = 0; r < 4; r++) {
          const float t = acc[i][j][r] + bj;
          ob[(m0 + r) * (long)N + c] = f2b(0.5f * t * (1.f + erff(t * 0.70710678f)));
        }
      }
    }
  }
}

// ---------------- fused attention v7: head-softmax fully in-register ----------------
// Softmax axis = heads(16). Each wave computes QK^T for ALL 16 heads on its own
// (t16 x s16) fragment, so all 16 head-scores of a given (t,s) sit in the SAME
// lane+reg -> denominator = 15 register adds + 1 rcp. No cross-wave reduction,
// no red[] LDS, no per-head abuf round trip.
// Swapped MFMA operands (mfma(K,Q) -> C[row=s][col=t]) make each lane hold 4
// consecutive s for one t -> P written to LDS as packed b64 (cvt_pk_bf16 pairs).
// P LDS [16h][16t][128s] XOR-swizzled (byte ^= (t&7)<<4) both sides -> PV A-frag
// ds_read_b128 ~2-way. Q staged once in 64KB swizzled LDS (off the L1/K-V path).
// Block: 512thr = 8 waves; t-tile 32 (2 sub-tiles share one K-load and one V-load
// in regs -> halves the L2 K/V stream vs t16); s-half 512 (sp) in 4 windows of 128
// (8 waves x 16s). Grid 256 = (nb,sp) XCD-pinned combos x 32 t-tiles.
// bf16 partial O per sp -> reduce_o2 (unchanged).
__global__ __launch_bounds__(512, 2)
void attn_kernel(const unsigned short* __restrict__ Qb,
                 const unsigned short* __restrict__ Kb,
                 const unsigned short* __restrict__ Vt,
                 unsigned short* __restrict__ P0, unsigned short* __restrict__ P1) {
  const int id = blockIdx.x;
  const int combo = id & 7;
  const int nb = combo & 3;
  const int sp = combo >> 2;
  const int tile = id >> 3;                 // 0..31 (32-row t-tiles)
  const int tid = threadIdx.x, lane = tid & 63;
  const int w = __builtin_amdgcn_readfirstlane(tid >> 6);
  const int l15 = lane & 15, l4 = lane >> 4;
  const int t0 = tile * 32;
  const int sbase = sp * 512;

  __shared__ __align__(16) unsigned short Qs[16 * 32 * 64];   // 64 KB, swizzled rows
  __shared__ __align__(16) unsigned short Ps[16 * 16 * 128];  // 64 KB, swizzled rows

  const size_t bb = ((size_t)(nb * 16)) << 16;
  const unsigned short* qB = Qb + bb;
  const unsigned short* kB = Kb + bb;
  const unsigned short* vB = Vt + bb;

  // ---- stage Q[h][t(32)][d(64)] -> Qs (coalesced global, swizzled LDS writes) ----
#pragma unroll
  for (int kk = 0; kk < 8; kk++) {
    const int j = kk * 512 + tid;
    const int h = j >> 8, t = (j >> 3) & 31, d8 = j & 7;
    const int4 v = *(const int4*)(qB + ((size_t)h << 16) + (size_t)(t0 + t) * 64 + d8 * 8);
    *(int4*)((char*)Qs + h * 4096 + t * 128 + ((d8 * 16) ^ ((t & 7) << 4))) = v;
  }

  const int swz = (l15 & 7) << 4;                        // row key (row = l15 both sides)
  const int qrA = l15 * 128;                             // sub-tile A row byte
  const int qrB = (16 + l15) * 128;                      // sub-tile B row byte
  const int qo0 = (l4 * 16) ^ swz;                       // ks=0 d-offset
  const int qo1 = (64 + l4 * 16) ^ swz;                  // ks=1 d-offset
  const int pwb = l15 * 256 + (((w * 16 + l4 * 4) * 2) ^ swz);   // P write (b64)
  int pro[4];
#pragma unroll
  for (int ks = 0; ks < 4; ks++) pro[ks] = l15 * 256 + ((ks * 64 + l4 * 16) ^ swz);

  const int h0 = w * 2;                                  // PV heads of this wave
  facc4 oacc[2][2][4];                                   // [hh][st][nt]
#pragma unroll
  for (int hh = 0; hh < 2; hh++)
#pragma unroll
    for (int st = 0; st < 2; st++)
#pragma unroll
      for (int nt = 0; nt < 4; nt++) oacc[hh][st][nt] = (facc4)0.f;

  __syncthreads();

  for (int it = 0; it < 4; ++it) {
    const int s0w = sbase + it * 128 + w * 16;
    // ---- QK^T: 16 heads x 2 sub-tiles; K loaded ONCE, shared across sub-tiles ----
    facc4 scA[16], scB[16];
#pragma unroll
    for (int h = 0; h < 16; h++) {
      const unsigned short* kh = kB + ((size_t)h << 16) + (size_t)(s0w + l15) * 64 + l4 * 8;
      const bfrag8 kf0 = *(const bfrag8*)kh;
      const bfrag8 kf1 = *(const bfrag8*)(kh + 32);
      const char* qh = (const char*)Qs + h * 4096;
      const bfrag8 qA0 = *(const bfrag8*)(qh + qrA + qo0);
      const bfrag8 qA1 = *(const bfrag8*)(qh + qrA + qo1);
      const bfrag8 qB0 = *(const bfrag8*)(qh + qrB + qo0);
      const bfrag8 qB1 = *(const bfrag8*)(qh + qrB + qo1);
      facc4 a = __builtin_amdgcn_mfma_f32_16x16x32_bf16(kf0, qA0, (facc4)0.f, 0, 0, 0);
      scA[h] = __builtin_amdgcn_mfma_f32_16x16x32_bf16(kf1, qA1, a, 0, 0, 0);
      facc4 b = __builtin_amdgcn_mfma_f32_16x16x32_bf16(kf0, qB0, (facc4)0.f, 0, 0, 0);
      scB[h] = __builtin_amdgcn_mfma_f32_16x16x32_bf16(kf1, qB1, b, 0, 0, 0);
    }
    // ---- softmax over heads (pure register), sub-tile A -> Ps ----
    {
      float d0 = 0.f, d1 = 0.f, d2 = 0.f, d3 = 0.f;
#pragma unroll
      for (int h = 0; h < 16; h++) {
        scA[h][0] = __expf(scA[h][0]); d0 += scA[h][0];
        scA[h][1] = __expf(scA[h][1]); d1 += scA[h][1];
        scA[h][2] = __expf(scA[h][2]); d2 += scA[h][2];
        scA[h][3] = __expf(scA[h][3]); d3 += scA[h][3];
      }
      const float r0 = 1.f / d0, r1 = 1.f / d1, r2 = 1.f / d2, r3 = 1.f / d3;
#pragma unroll
      for (int h = 0; h < 16; h++) {
        const float p0 = scA[h][0] * r0, p1 = scA[h][1] * r1;
        const float p2 = scA[h][2] * r2, p3 = scA[h][3] * r3;
        uint2 pk;
        asm("v_cvt_pk_bf16_f32 %0, %1, %2" : "=v"(pk.x) : "v"(p0), "v"(p1));
        asm("v_cvt_pk_bf16_f32 %0, %1, %2" : "=v"(pk.y) : "v"(p2), "v"(p3));
        *(uint2*)((char*)Ps + h * 4096 + pwb) = pk;
      }
    }
    __syncthreads();                                     // B1: P(A) visible
    bfrag8 afA[2][4];
#pragma unroll
    for (int hh = 0; hh < 2; hh++)
#pragma unroll
      for (int ks = 0; ks < 4; ks++)
        afA[hh][ks] = *(const bfrag8*)((char*)Ps + (h0 + hh) * 4096 + pro[ks]);
    __syncthreads();                                     // B2: Ps free
    // ---- softmax sub-tile B -> Ps ----
    {
      float d0 = 0.f, d1 = 0.f, d2 = 0.f, d3 = 0.f;
#pragma unroll
      for (int h = 0; h < 16; h++) {
        scB[h][0] = __expf(scB[h][0]); d0 += scB[h][0];
        scB[h][1] = __expf(scB[h][1]); d1 += scB[h][1];
        scB[h][2] = __expf(scB[h][2]); d2 += scB[h][2];
        scB[h][3] = __expf(scB[h][3]); d3 += scB[h][3];
      }
      const float r0 = 1.f / d0, r1 = 1.f / d1, r2 = 1.f / d2, r3 = 1.f / d3;
#pragma unroll
      for (int h = 0; h < 16; h++) {
        const float p0 = scB[h][0] * r0, p1 = scB[h][1] * r1;
        const float p2 = scB[h][2] * r2, p3 = scB[h][3] * r3;
        uint2 pk;
        asm("v_cvt_pk_bf16_f32 %0, %1, %2" : "=v"(pk.x) : "v"(p0), "v"(p1));
        asm("v_cvt_pk_bf16_f32 %0, %1, %2" : "=v"(pk.y) : "v"(p2), "v"(p3));
        *(uint2*)((char*)Ps + h * 4096 + pwb) = pk;
      }
    }
    __syncthreads();                                     // B3: P(B) visible
    bfrag8 afB[2][4];
#pragma unroll
    for (int hh = 0; hh < 2; hh++)
#pragma unroll
      for (int ks = 0; ks < 4; ks++)
        afB[hh][ks] = *(const bfrag8*)((char*)Ps + (h0 + hh) * 4096 + pro[ks]);
    __syncthreads();                                     // B4: Ps free for next window
    // ---- PV both sub-tiles; V loaded ONCE, shared across sub-tiles ----
#pragma unroll
    for (int hh = 0; hh < 2; hh++) {
      const unsigned short* vh = vB + ((size_t)(h0 + hh) << 16) + sbase + it * 128 + l4 * 8;
#pragma unroll
      for (int ks = 0; ks < 4; ks++)
#pragma unroll
        for (int nt = 0; nt < 4; nt++) {
          const bfrag8 vf = *(const bfrag8*)(vh + (size_t)(nt * 16 + l15) * 1024 + ks * 32);
          oacc[hh][0][nt] =
              __builtin_amdgcn_mfma_f32_16x16x32_bf16(afA[hh][ks], vf, oacc[hh][0][nt], 0, 0, 0);
          oacc[hh][1][nt] =
              __builtin_amdgcn_mfma_f32_16x16x32_bf16(afB[hh][ks], vf, oacc[hh][1][nt], 0, 0, 0);
        }
    }
  }

  // ---- bf16 partial O through the raw-reshape flat view ----
  unsigned short* P = sp ? P1 : P0;
#pragma unroll
  for (int hh = 0; hh < 2; hh++) {
    const size_t hb = ((size_t)nb << 20) + ((size_t)(h0 + hh) << 16);
#pragma unroll
    for (int st = 0; st < 2; st++)
#pragma unroll
      for (int nt = 0; nt < 4; nt++)
#pragma unroll
        for (int r = 0; r < 4; r++)
          P[hb + (size_t)(t0 + st * 16 + l4 * 4 + r) * 64 + nt * 16 + l15] =
              f2b(oacc[hh][st][nt][r]);
  }
}

// ---------------- reduce 2 bf16 partials -> bf16 ----------------
__global__ __launch_bounds__(256)
void reduce_o2(const unsigned short* __restrict__ P0, const unsigned short* __restrict__ P1,
               unsigned short* __restrict__ OB, int n4) {
  const int i = blockIdx.x * 256 + threadIdx.x;
  if (i < n4) {
    const ushort4 a = ((const ushort4*)P0)[i];
    const ushort4 b = ((const ushort4*)P1)[i];
    ushort4 u;
    u.x = f2b(b2f(a.x) + b2f(b.x));
    u.y = f2b(b2f(a.y) + b2f(b.y));
    u.z = f2b(b2f(a.z) + b2f(b.z));
    u.w = f2b(b2f(a.w) + b2f(b.w));
    ((ushort4*)OB)[i] = u;
  }
}

// ---- LayerNorm reducing 4 bf16 GEMM partials + bias + residual: out = LN(sum+b+res) ----
__global__ __launch_bounds__(256)
void ln_red(const unsigned short* __restrict__ P0, const unsigned short* __restrict__ P1,
            const unsigned short* __restrict__ P2, const unsigned short* __restrict__ P3,
            const float* __restrict__ bias, const float* __restrict__ resid,
            const float* __restrict__ g, const float* __restrict__ be,
            float* __restrict__ outf, unsigned short* __restrict__ outb) {
  const int row = blockIdx.x, tid = threadIdx.x;
  const size_t o4 = (size_t)row * 256 + tid;
  const ushort4 a = ((const ushort4*)P0)[o4];
  const ushort4 b = ((const ushort4*)P1)[o4];
  const ushort4 c = ((const ushort4*)P2)[o4];
  const ushort4 d = ((const ushort4*)P3)[o4];
  const float4 vb = ((const float4*)bias)[tid];
  const float4 vr = ((const float4*)resid)[o4];
  float t0 = b2f(a.x) + b2f(b.x) + b2f(c.x) + b2f(d.x) + vb.x + vr.x;
  float t1 = b2f(a.y) + b2f(b.y) + b2f(c.y) + b2f(d.y) + vb.y + vr.y;
  float t2 = b2f(a.z) + b2f(b.z) + b2f(c.z) + b2f(d.z) + vb.z + vr.z;
  float t3 = b2f(a.w) + b2f(b.w) + b2f(c.w) + b2f(d.w) + vb.w + vr.w;
  float s = t0 + t1 + t2 + t3;
  float q = t0 * t0 + t1 * t1 + t2 * t2 + t3 * t3;
#pragma unroll
  for (int off = 32; off > 0; off >>= 1) {
    s += __shfl_down(s, off, 64);
    q += __shfl_down(q, off, 64);
  }
  __shared__ float rs_[4], rq_[4];
  if ((tid & 63) == 0) { rs_[tid >> 6] = s; rq_[tid >> 6] = q; }
  __syncthreads();
  const float S = rs_[0] + rs_[1] + rs_[2] + rs_[3];
  const float Q = rq_[0] + rq_[1] + rq_[2] + rq_[3];
  const float mean = S * (1.f / 1024.f);
  const float var  = Q * (1.f / 1024.f) - mean * mean;
  const float rstd = rsqrtf(var + 1e-5f);
  const float4 vg  = ((const float4*)g)[tid];
  const float4 vbe = ((const float4*)be)[tid];
  float o0 = (t0 - mean) * rstd * vg.x + vbe.x;
  float o1 = (t1 - mean) * rstd * vg.y + vbe.y;
  float o2 = (t2 - mean) * rstd * vg.z + vbe.z;
  float o3 = (t3 - mean) * rstd * vg.w + vbe.w;
  ((float4*)(outf + (size_t)row * 1024))[tid] = make_float4(o0, o1, o2, o3);
  if (outb != nullptr) {
    ushort4 u;
    u.x = f2b(o0); u.y = f2b(o1); u.z = f2b(o2); u.w = f2b(o3);
    ((ushort4*)(outb + (size_t)row * 1024))[tid] = u;
  }
}

// ---------------- launch ----------------
extern "C" void kernel_launch(void* const* d_in, const int* in_sizes, int n_in,
                              void* d_out, int out_size, void* d_ws, size_t ws_size,
                              hipStream_t stream) {
  const float* x  = (const float*)d_in[0];
  const float* Wq = (const float*)d_in[1];
  const float* bq = (const float*)d_in[2];
  const float* Wk = (const float*)d_in[3];
  const float* bk = (const float*)d_in[4];
  const float* Wv = (const float*)d_in[5];
  const float* bv = (const float*)d_in[6];
  const float* Wo = (const float*)d_in[7];
  const float* bo = (const float*)d_in[8];
  const float* g1 = (const float*)d_in[9];
  const float* b1 = (const float*)d_in[10];
  const float* W1 = (const float*)d_in[11];
  const float* c1 = (const float*)d_in[12];
  const float* W2 = (const float*)d_in[13];
  const float* c2 = (const float*)d_in[14];
  const float* g2 = (const float*)d_in[15];
  const float* b2 = (const float*)d_in[16];
  float* out = (float*)d_out;

  char* ws = (char*)d_ws;
  unsigned short* XB  = (unsigned short*)(ws);              // 8MB  x bf16
  unsigned short* WQT = (unsigned short*)(ws + 8388608);    // 2MB
  unsigned short* WKT = (unsigned short*)(ws + 10485760);   // 2MB
  unsigned short* WVT = (unsigned short*)(ws + 12582912);   // 2MB
  unsigned short* WOT = (unsigned short*)(ws + 14680064);   // 2MB
  unsigned short* W1T = (unsigned short*)(ws + 16777216);   // 8MB
  unsigned short* W2T = (unsigned short*)(ws + 25165824);   // 8MB
  float*          X1  = (float*)(ws + 33554432);            // 16MB fp32 (LN1 out)
  unsigned short* X1B = (unsigned short*)(ws + 50331648);   // 8MB
  char* RB = ws + 58720256;                                 // 48MB union region
  unsigned short* QB  = (unsigned short*)(RB);              // 8MB
  unsigned short* KB  = (unsigned short*)(RB + 8388608);    // 8MB
  unsigned short* VT  = (unsigned short*)(RB + 16777216);   // 8MB
  unsigned short* OB  = (unsigned short*)(RB + 25165824);   // 8MB
  unsigned short* H1B = (unsigned short*)(RB);              // 32MB FFN phase (= QB..OB)
  // attn bf16 partials in dead OWO region
  unsigned short* AP0 = (unsigned short*)(RB + 33554432);
  unsigned short* AP1 = (unsigned short*)(RB + 41943040);
  // o-proj split-K partials (QB/KB/VT free after attn; XB free after QKV)
  PtrQuad OPQ = { { QB, KB, VT, XB } };
  // FFN2 split-K partials (XB,X1B free; OWO region free)
  PtrQuad FPQ = { { XB, X1B, (unsigned short*)(RB + 33554432),
                    (unsigned short*)(RB + 41943040) } };
  PtrQuad ZQ = { { nullptr, nullptr, nullptr, nullptr } };

  const dim3 tb(256);
  cvt_bf16_kernel<<<dim3(4096), tb, 0, stream>>>(x, XB, 1048576);
  transpose_cvt<<<dim3(32, 32),  tb, 0, stream>>>(Wq, WQT, 1024, 1024);
  transpose_cvt<<<dim3(32, 32),  tb, 0, stream>>>(Wk, WKT, 1024, 1024);
  transpose_cvt<<<dim3(32, 32),  tb, 0, stream>>>(Wv, WVT, 1024, 1024);
  transpose_cvt<<<dim3(32, 32),  tb, 0, stream>>>(Wo, WOT, 1024, 1024);
  transpose_cvt<<<dim3(128, 32), tb, 0, stream>>>(W1, W1T, 1024, 4096);
  transpose_cvt<<<dim3(32, 128), tb, 0, stream>>>(W2, W2T, 4096, 1024);
  // QKV (N=3072): epilogue scatters Q(scaled), K, V(per-head transposed)
  gemm_bt<EPI_QKV><<<dim3(24, 32), tb, 0, stream>>>(XB, WQT, bq, bk, bv, (void*)QB, ZQ,
                                                    4096, 3072, 1024, 1024);
  // attention v7: 256 blocks x 512 thr, (nb,sp) XCD-pinned, bf16 partials
  attn_kernel<<<dim3(256), dim3(512), 0, stream>>>(QB, KB, VT, AP0, AP1);
  reduce_o2<<<dim3(4096), tb, 0, stream>>>(AP0, AP1, OB, 1048576);
  // O-proj: split-K=4 (kLen 256) -> bf16 partials; reduce+bias+residual fused in LN1
  gemm_bt<EPI_PART><<<dim3(8, 32, 4), tb, 0, stream>>>(OB, WOT, nullptr, nullptr, nullptr,
                                                       nullptr, OPQ, 4096, 1024, 256, 1024);
  ln_red<<<dim3(4096), tb, 0, stream>>>(QB, KB, VT, XB, bo, x, g1, b1, X1, X1B);
  // FFN1 + exact GELU -> bf16
  gemm_bt<EPI_GELU><<<dim3(32, 32), tb, 0, stream>>>(X1B, W1T, c1, nullptr, nullptr,
                                                     (void*)H1B, ZQ, 4096, 4096, 1024, 1024);
  // FFN2: split-K=4 (kLen 1024) -> bf16 partials; reduce+bias+residual fused in LN2
  gemm_bt<EPI_PART><<<dim3(8, 32, 4), tb, 0, stream>>>(H1B, W2T, nullptr, nullptr, nullptr,
                                                       nullptr, FPQ, 4096, 1024, 1024, 4096);
  ln_red<<<dim3(4096), tb, 0, stream>>>(FPQ.p[0], FPQ.p[1], FPQ.p[2], FPQ.p[3], c2, X1,
                                        g2, b2, out, (unsigned short*)nullptr);
}